// Round 3
// baseline (466.365 us; speedup 1.0000x reference)
//
#include <hip/hip_runtime.h>

// MoE top-2 FFN, split-bf16 MFMA. Round 3:
//  - k_prep pre-splits x to bf16 hi/lo (no conversion VALU in GEMM loops)
//  - both GEMMs: T3-minimal pipeline (dbuf LDS, stage(next) || MFMA(cur), 1 barrier/kstep)
//  - unified 128B LDS rows [hi64|lo64], kstep=32, XOR swizzle, all-DMA staging
//  - ffn1 128x128 4-wave (2 blk/CU), ffn2 64x256 k-split x4 4-wave (2 blk/CU)

#define T_TOKENS 4096
#define D_MOD 512
#define N_EXP 8
#define D_FF 2048
#define TPAD 128
#define P_CAP 9216       // 72*128 >= 8192 + 8*127

typedef __attribute__((ext_vector_type(4))) float f32x4_t;
typedef __attribute__((ext_vector_type(8))) short sh8;
typedef __attribute__((ext_vector_type(4))) unsigned short us4;

__device__ __forceinline__ unsigned short f2bh(float f) {
  unsigned u = __float_as_uint(f);
  return (unsigned short)((u + 0x7FFFu + ((u >> 16) & 1u)) >> 16);  // RNE
}
__device__ __forceinline__ float bh2f(unsigned short h) {
  return __uint_as_float(((unsigned)h) << 16);
}
__device__ __forceinline__ void gl_lds16(const void* g, void* l) {
  __builtin_amdgcn_global_load_lds(
      (const __attribute__((address_space(1))) unsigned int*)g,
      (__attribute__((address_space(3))) unsigned int*)l, 16, 0, 0);
}

// ---------------- routing ----------------

__global__ void k_init(int* counts, int* pair_token, float* pair_gate) {
  int idx = blockIdx.x * 256 + threadIdx.x;
  if (idx < P_CAP) { pair_token[idx] = -1; pair_gate[idx] = 0.f; }
  if (idx < N_EXP) counts[idx] = 0;
}

__global__ __launch_bounds__(256) void k_prep(const float* __restrict__ x,
    unsigned short* __restrict__ xh, unsigned short* __restrict__ xl) {
  int i = (blockIdx.x * 256 + threadIdx.x) * 8;   // 2,097,152 elems total
  float4 a = *(const float4*)(x + i);
  float4 b = *(const float4*)(x + i + 4);
  us4 h0 = {f2bh(a.x), f2bh(a.y), f2bh(a.z), f2bh(a.w)};
  us4 h1 = {f2bh(b.x), f2bh(b.y), f2bh(b.z), f2bh(b.w)};
  us4 l0 = {f2bh(a.x - bh2f(h0.x)), f2bh(a.y - bh2f(h0.y)),
            f2bh(a.z - bh2f(h0.z)), f2bh(a.w - bh2f(h0.w))};
  us4 l1 = {f2bh(b.x - bh2f(h1.x)), f2bh(b.y - bh2f(h1.y)),
            f2bh(b.z - bh2f(h1.z)), f2bh(b.w - bh2f(h1.w))};
  *(us4*)(xh + i) = h0; *(us4*)(xh + i + 4) = h1;
  *(us4*)(xl + i) = l0; *(us4*)(xl + i + 4) = l1;
}

__global__ __launch_bounds__(256) void k_gate(const float* __restrict__ x,
    const float* __restrict__ Wg, const float* __restrict__ bg,
    int* __restrict__ top_i, float* __restrict__ gates, int* __restrict__ counts) {
  __shared__ float wg_s[D_MOD * N_EXP];
  int tid = threadIdx.x;
  for (int i = tid; i < D_MOD * N_EXP; i += 256)
    wg_s[(i & 7) * D_MOD + (i >> 3)] = Wg[i];
  __syncthreads();
  int lane = tid & 63, w = tid >> 6;
  int t = blockIdx.x * 4 + w;
  const float* xr = x + (size_t)t * D_MOD;
  float acc[8];
#pragma unroll
  for (int e = 0; e < 8; ++e) acc[e] = 0.f;
#pragma unroll
  for (int it = 0; it < 2; ++it) {
    int d = it * 256 + lane * 4;
    float4 xv = *(const float4*)(xr + d);
#pragma unroll
    for (int e = 0; e < 8; ++e) {
      float4 wv = *(const float4*)(wg_s + e * D_MOD + d);
      acc[e] += xv.x * wv.x + xv.y * wv.y + xv.z * wv.z + xv.w * wv.w;
    }
  }
#pragma unroll
  for (int m = 32; m >= 1; m >>= 1)
#pragma unroll
    for (int e = 0; e < 8; ++e) acc[e] += __shfl_xor(acc[e], m);
  if (lane == 0) {
#pragma unroll
    for (int e = 0; e < 8; ++e) acc[e] += bg[e];
    int e0 = 0; float m0 = acc[0];
#pragma unroll
    for (int e = 1; e < 8; ++e) if (acc[e] > m0) { m0 = acc[e]; e0 = e; }
    int e1 = -1; float m1 = -3.4e38f;
#pragma unroll
    for (int e = 0; e < 8; ++e) if (e != e0 && acc[e] > m1) { m1 = acc[e]; e1 = e; }
    float g0 = 1.f / (1.f + __expf(m1 - m0));
    float g1 = 1.f - g0;
    top_i[t * 2] = e0; top_i[t * 2 + 1] = e1;
    gates[t * 2] = g0; gates[t * 2 + 1] = g1;
    atomicAdd(&counts[e0], 1);
    atomicAdd(&counts[e1], 1);
  }
}

__global__ void k_scan(const int* counts, int* offsets, int* cursor) {
  if (threadIdx.x == 0 && blockIdx.x == 0) {
    int o = 0;
    for (int e = 0; e < N_EXP; ++e) {
      offsets[e] = o; cursor[e] = o;
      o += (counts[e] + TPAD - 1) & ~(TPAD - 1);
    }
    offsets[N_EXP] = o;
  }
}

__global__ void k_scatter(const int* top_i, const float* gates, int* cursor,
                          int* pair_token, float* pair_gate) {
  int t = blockIdx.x * 256 + threadIdx.x;
#pragma unroll
  for (int k = 0; k < 2; ++k) {
    int e = top_i[t * 2 + k];
    int pos = atomicAdd(&cursor[e], 1);
    pair_token[pos] = t;
    pair_gate[pos] = gates[t * 2 + k];
  }
}

__global__ void k_outinit(const int* __restrict__ top_i, const float* __restrict__ gates,
                          const float* __restrict__ b2, float* __restrict__ out) {
  int idx = blockIdx.x * 256 + threadIdx.x;
  int t = idx >> 9, d = idx & 511;
  out[idx] = gates[t * 2] * b2[top_i[t * 2] * D_MOD + d] +
             gates[t * 2 + 1] * b2[top_i[t * 2 + 1] * D_MOD + d];
}

// -------- weight transpose + hi/lo split: W[e][R][C] -> Wt[e][C][R] --------

__global__ __launch_bounds__(256) void k_transpose(const float* __restrict__ W,
    unsigned short* __restrict__ Wh, unsigned short* __restrict__ Wl, int R, int C) {
  __shared__ float tile[32][33];
  int e = blockIdx.z;
  int c0 = blockIdx.x * 32, r0 = blockIdx.y * 32;
  const float* src = W + (size_t)e * R * C;
  int tx = threadIdx.x & 31, ty = threadIdx.x >> 5;
#pragma unroll
  for (int i = 0; i < 4; ++i) {
    int r = ty + i * 8;
    tile[r][tx] = src[(size_t)(r0 + r) * C + c0 + tx];
  }
  __syncthreads();
  int cl = threadIdx.x >> 3;
  int r4 = (threadIdx.x & 7) * 4;
  float v0 = tile[r4 + 0][cl], v1 = tile[r4 + 1][cl];
  float v2 = tile[r4 + 2][cl], v3 = tile[r4 + 3][cl];
  us4 hv = {f2bh(v0), f2bh(v1), f2bh(v2), f2bh(v3)};
  us4 lv = {f2bh(v0 - bh2f(hv.x)), f2bh(v1 - bh2f(hv.y)),
            f2bh(v2 - bh2f(hv.z)), f2bh(v3 - bh2f(hv.w))};
  size_t o = ((size_t)e * C + c0 + cl) * R + r0 + r4;
  *(us4*)(Wh + o) = hv;
  *(us4*)(Wl + o) = lv;
}

// -------- GEMM1: h = relu(x @ W1 + b1), 128x128 tile, 4 waves, kstep 32 --------
// LDS row format: 128B = [hi 64B | lo 64B], slot s (16B) holds source chunk s^(row&7).

__global__ __launch_bounds__(256, 2) void k_ffn1(
    const unsigned short* __restrict__ xh, const unsigned short* __restrict__ xl,
    const unsigned short* __restrict__ W1h, const unsigned short* __restrict__ W1l,
    const float* __restrict__ b1, const int* __restrict__ pair_token,
    const int* __restrict__ offsets, unsigned short* __restrict__ h_hi,
    unsigned short* __restrict__ h_lo, int row_base) {
  int total = offsets[N_EXP];
  int row0 = row_base + blockIdx.x * TPAD;
  if (row0 >= total) return;
  int f0 = blockIdx.y * 128;
  int e = 0;
  while (offsets[e + 1] <= row0) ++e;

  __shared__ __align__(16) char lds[65536 + 512];   // 2 x (A 16KB + B 16KB) + tok
  int* tok = (int*)(lds + 65536);
  int tid = threadIdx.x;
  if (tid < TPAD) { int t = pair_token[row0 + tid]; tok[tid] = t < 0 ? 0 : t; }
  __syncthreads();

  // static DMA descriptors: idx = tid + i*256 -> row rq+32i, slot s=tid&7 (const)
  int s = tid & 7, rq = tid >> 3;                 // rq 0..31
  int c = s ^ (rq & 7);                           // source chunk, const across i
  const unsigned short* bA = (c < 4) ? xh : xl;
  const unsigned short* bB = (c < 4) ? W1h : W1l;
  size_t wb = (size_t)e * D_FF * D_MOD;
  const char* srcA[4]; const char* srcB[4];
#pragma unroll
  for (int i = 0; i < 4; ++i) {
    srcA[i] = (const char*)(bA + (size_t)tok[rq + i * 32] * D_MOD + (c & 3) * 8);
    srcB[i] = (const char*)(bB + wb + (size_t)(f0 + rq + i * 32) * D_MOD + (c & 3) * 8);
  }

  auto stage = [&](int bb, int ks) {
    char* Ad = lds + bb * 32768;
    char* Bd = Ad + 16384;
    int kb = ks * 64;   // 32 elems * 2B
#pragma unroll
    for (int i = 0; i < 4; ++i) gl_lds16(srcA[i] + kb, Ad + tid * 16 + i * 4096);
#pragma unroll
    for (int i = 0; i < 4; ++i) gl_lds16(srcB[i] + kb, Bd + tid * 16 + i * 4096);
  };

  int lane = tid & 63, wid = tid >> 6;
  int wr = wid & 1, wc = wid >> 1;                // 2x2 wave grid, 64x64 wave tile
  int lrow = lane & 15, kblk = lane >> 4;
  const f32x4_t zero = {0.f, 0.f, 0.f, 0.f};
  f32x4_t acc[4][4];
#pragma unroll
  for (int a = 0; a < 4; ++a)
#pragma unroll
    for (int b = 0; b < 4; ++b) acc[a][b] = zero;

  stage(0, 0);
  __syncthreads();
  for (int ks = 0; ks < 16; ++ks) {
    int bb = ks & 1;
    if (ks < 15) stage(bb ^ 1, ks + 1);
    const char* Ab = lds + bb * 32768;
    const char* Bb = Ab + 16384;
    sh8 ah[4], al[4], bh[4], bl[4];
#pragma unroll
    for (int rt = 0; rt < 4; ++rt) {
      int row = wr * 64 + rt * 16 + lrow;
      int base = row * 128;
      ah[rt] = *(const sh8*)(Ab + base + ((kblk ^ (row & 7)) << 4));
      al[rt] = *(const sh8*)(Ab + base + (((kblk + 4) ^ (row & 7)) << 4));
    }
#pragma unroll
    for (int ct = 0; ct < 4; ++ct) {
      int row = wc * 64 + ct * 16 + lrow;
      int base = row * 128;
      bh[ct] = *(const sh8*)(Bb + base + ((kblk ^ (row & 7)) << 4));
      bl[ct] = *(const sh8*)(Bb + base + (((kblk + 4) ^ (row & 7)) << 4));
    }
#pragma unroll
    for (int rt = 0; rt < 4; ++rt)
#pragma unroll
      for (int ct = 0; ct < 4; ++ct) {
        acc[rt][ct] = __builtin_amdgcn_mfma_f32_16x16x32_bf16(ah[rt], bh[ct], acc[rt][ct], 0, 0, 0);
        acc[rt][ct] = __builtin_amdgcn_mfma_f32_16x16x32_bf16(ah[rt], bl[ct], acc[rt][ct], 0, 0, 0);
        acc[rt][ct] = __builtin_amdgcn_mfma_f32_16x16x32_bf16(al[rt], bh[ct], acc[rt][ct], 0, 0, 0);
      }
    __syncthreads();
  }

  // epilogue: relu(+b1), split hi/lo, vectorized store via LDS (two 64-col halves)
  float b1v[4];
#pragma unroll
  for (int ct = 0; ct < 4; ++ct)
    b1v[ct] = b1[e * D_FF + f0 + wc * 64 + ct * 16 + lrow];
  int crow = row0 - row_base;
  float* hs = (float*)lds;                        // 128 x 64 f32 = 32KB
#pragma unroll
  for (int hf = 0; hf < 2; ++hf) {
    __syncthreads();
    if (wc == hf) {
#pragma unroll
      for (int rt = 0; rt < 4; ++rt)
#pragma unroll
        for (int ct = 0; ct < 4; ++ct)
#pragma unroll
          for (int j = 0; j < 4; ++j) {
            int row = wr * 64 + rt * 16 + kblk * 4 + j;   // C/D: row=(l>>4)*4+reg
            int col = ct * 16 + lrow;                     // col = l&15
            float v = fmaxf(acc[rt][ct][j] + b1v[ct], 0.f);
            int c4 = col >> 2;
            hs[row * 64 + ((c4 ^ ((row & 3) << 2)) << 2) + (col & 3)] = v;
          }
    }
    __syncthreads();
#pragma unroll
    for (int i = 0; i < 8; ++i) {
      int idx = tid + i * 256;                    // 2048 float4
      int r = idx >> 4, c4 = idx & 15;
      float4 v = *(const float4*)(hs + r * 64 + ((c4 ^ ((r & 3) << 2)) << 2));
      us4 hv = {f2bh(v.x), f2bh(v.y), f2bh(v.z), f2bh(v.w)};
      us4 lv = {f2bh(v.x - bh2f(hv.x)), f2bh(v.y - bh2f(hv.y)),
                f2bh(v.z - bh2f(hv.z)), f2bh(v.w - bh2f(hv.w))};
      size_t o = (size_t)(crow + r) * D_FF + f0 + hf * 64 + c4 * 4;
      *(us4*)(h_hi + o) = hv;
      *(us4*)(h_lo + o) = lv;
    }
  }
}

// -------- GEMM2: out += gate * (h @ W2), 64x256 tile, k-split x4, 4 waves --------

__global__ __launch_bounds__(256, 2) void k_ffn2(
    const unsigned short* __restrict__ h_hi, const unsigned short* __restrict__ h_lo,
    const unsigned short* __restrict__ W2h, const unsigned short* __restrict__ W2l,
    const int* __restrict__ pair_token, const float* __restrict__ pair_gate,
    const int* __restrict__ offsets, float* __restrict__ out, int row_base) {
  int total = offsets[N_EXP];
  int row0 = row_base + blockIdx.x * 64;
  if (row0 >= total) return;
  int n0 = blockIdx.y * 256;
  int kc = blockIdx.z * 512;
  int e = 0;
  while (offsets[e + 1] <= row0) ++e;

  __shared__ __align__(16) char lds[81920];       // 2 x (A 8KB + B 32KB) = 160KB/2 exactly
  int tid = threadIdx.x;
  int crow = row0 - row_base;

  int s = tid & 7, rq = tid >> 3;                 // rq 0..31
  int c = s ^ (rq & 7);
  const unsigned short* bA = (c < 4) ? h_hi : h_lo;
  const unsigned short* bB = (c < 4) ? W2h : W2l;
  size_t wb = (size_t)e * D_MOD * D_FF;
  const char* srcA[2]; const char* srcB[8];
#pragma unroll
  for (int i = 0; i < 2; ++i)
    srcA[i] = (const char*)(bA + (size_t)(crow + rq + i * 32) * D_FF + kc + (c & 3) * 8);
#pragma unroll
  for (int i = 0; i < 8; ++i)
    srcB[i] = (const char*)(bB + wb + (size_t)(n0 + rq + i * 32) * D_FF + kc + (c & 3) * 8);

  auto stage = [&](int bb, int ks) {
    char* Ad = lds + bb * 40960;
    char* Bd = Ad + 8192;
    int kb = ks * 64;
#pragma unroll
    for (int i = 0; i < 2; ++i) gl_lds16(srcA[i] + kb, Ad + tid * 16 + i * 4096);
#pragma unroll
    for (int i = 0; i < 8; ++i) gl_lds16(srcB[i] + kb, Bd + tid * 16 + i * 4096);
  };

  int lane = tid & 63, wc = tid >> 6;             // 1x4 wave grid, 64x64 wave tile
  int lrow = lane & 15, kblk = lane >> 4;
  const f32x4_t zero = {0.f, 0.f, 0.f, 0.f};
  f32x4_t acc[4][4];
#pragma unroll
  for (int a = 0; a < 4; ++a)
#pragma unroll
    for (int b = 0; b < 4; ++b) acc[a][b] = zero;

  stage(0, 0);
  __syncthreads();
  for (int ks = 0; ks < 16; ++ks) {
    int bb = ks & 1;
    if (ks < 15) stage(bb ^ 1, ks + 1);
    const char* Ab = lds + bb * 40960;
    const char* Bb = Ab + 8192;
    sh8 ah[4], al[4], bh[4], bl[4];
#pragma unroll
    for (int rt = 0; rt < 4; ++rt) {
      int row = rt * 16 + lrow;
      int base = row * 128;
      ah[rt] = *(const sh8*)(Ab + base + ((kblk ^ (row & 7)) << 4));
      al[rt] = *(const sh8*)(Ab + base + (((kblk + 4) ^ (row & 7)) << 4));
    }
#pragma unroll
    for (int ct = 0; ct < 4; ++ct) {
      int row = wc * 64 + ct * 16 + lrow;
      int base = row * 128;
      bh[ct] = *(const sh8*)(Bb + base + ((kblk ^ (row & 7)) << 4));
      bl[ct] = *(const sh8*)(Bb + base + (((kblk + 4) ^ (row & 7)) << 4));
    }
#pragma unroll
    for (int rt = 0; rt < 4; ++rt)
#pragma unroll
      for (int ct = 0; ct < 4; ++ct) {
        acc[rt][ct] = __builtin_amdgcn_mfma_f32_16x16x32_bf16(ah[rt], bh[ct], acc[rt][ct], 0, 0, 0);
        acc[rt][ct] = __builtin_amdgcn_mfma_f32_16x16x32_bf16(ah[rt], bl[ct], acc[rt][ct], 0, 0, 0);
        acc[rt][ct] = __builtin_amdgcn_mfma_f32_16x16x32_bf16(al[rt], bh[ct], acc[rt][ct], 0, 0, 0);
      }
    __syncthreads();
  }

#pragma unroll
  for (int rt = 0; rt < 4; ++rt)
#pragma unroll
    for (int j = 0; j < 4; ++j) {
      int row = rt * 16 + kblk * 4 + j;
      int t_ = pair_token[row0 + row];
      if (t_ >= 0) {
        float g = pair_gate[row0 + row];
#pragma unroll
        for (int ct = 0; ct < 4; ++ct) {
          int n = n0 + wc * 64 + ct * 16 + lrow;
          atomicAdd(out + (size_t)t_ * D_MOD + n, g * acc[rt][ct][j]);
        }
      }
    }
}

// ---------------- launch ----------------

extern "C" void kernel_launch(void* const* d_in, const int* in_sizes, int n_in,
                              void* d_out, int out_size, void* d_ws, size_t ws_size,
                              hipStream_t stream) {
  const float* x  = (const float*)d_in[0];
  const float* Wg = (const float*)d_in[1];
  const float* bg = (const float*)d_in[2];
  const float* W1 = (const float*)d_in[3];
  const float* b1 = (const float*)d_in[4];
  const float* W2 = (const float*)d_in[5];
  const float* b2 = (const float*)d_in[6];
  float* out = (float*)d_out;

  char* ws = (char*)d_ws;
  size_t off = 0;
  auto take = [&](size_t bytes) -> char* {
    char* p = ws + off;
    off += (bytes + 255) & ~(size_t)255;
    return p;
  };
  const size_t WELEMS = (size_t)N_EXP * D_MOD * D_FF;
  unsigned short* W1h = (unsigned short*)take(WELEMS * 2);
  unsigned short* W1l = (unsigned short*)take(WELEMS * 2);
  unsigned short* W2h = (unsigned short*)take(WELEMS * 2);
  unsigned short* W2l = (unsigned short*)take(WELEMS * 2);
  unsigned short* xh  = (unsigned short*)take((size_t)T_TOKENS * D_MOD * 2);
  unsigned short* xl  = (unsigned short*)take((size_t)T_TOKENS * D_MOD * 2);
  int*   top_i      = (int*)take((size_t)T_TOKENS * 2 * 4);
  float* gates      = (float*)take((size_t)T_TOKENS * 2 * 4);
  int*   counts     = (int*)take(64);
  int*   offsets    = (int*)take(64);
  int*   cursor     = (int*)take(64);
  int*   pair_token = (int*)take((size_t)P_CAP * 4);
  float* pair_gate  = (float*)take((size_t)P_CAP * 4);
  size_t h_avail = (ws_size > off) ? ws_size - off : 0;
  int rows_cap = (int)(h_avail / ((size_t)D_FF * 4));   // hi+lo bf16 = 4B/elem
  rows_cap &= ~(TPAD - 1);
  if (rows_cap > P_CAP) rows_cap = P_CAP;
  if (rows_cap < TPAD) rows_cap = TPAD;
  unsigned short* h_hi = (unsigned short*)(ws + off);
  unsigned short* h_lo = h_hi + (size_t)rows_cap * D_FF;

  k_init<<<dim3((P_CAP + 255) / 256), dim3(256), 0, stream>>>(counts, pair_token, pair_gate);
  k_prep<<<dim3(T_TOKENS * D_MOD / 2048), dim3(256), 0, stream>>>(x, xh, xl);
  k_gate<<<dim3(T_TOKENS / 4), dim3(256), 0, stream>>>(x, Wg, bg, top_i, gates, counts);
  k_scan<<<dim3(1), dim3(64), 0, stream>>>(counts, offsets, cursor);
  k_scatter<<<dim3(T_TOKENS / 256), dim3(256), 0, stream>>>(top_i, gates, cursor, pair_token, pair_gate);
  k_outinit<<<dim3(T_TOKENS * D_MOD / 256), dim3(256), 0, stream>>>(top_i, gates, b2, out);
  k_transpose<<<dim3(D_FF / 32, D_MOD / 32, N_EXP), dim3(256), 0, stream>>>(W1, W1h, W1l, D_MOD, D_FF);
  k_transpose<<<dim3(D_MOD / 32, D_FF / 32, N_EXP), dim3(256), 0, stream>>>(W2, W2h, W2l, D_FF, D_MOD);

  for (int rb = 0; rb < P_CAP; rb += rows_cap) {
    int left = P_CAP - rb;
    int rows = (rows_cap < left) ? rows_cap : left;
    k_ffn1<<<dim3(rows / TPAD, D_FF / 128), dim3(256), 0, stream>>>(
        xh, xl, W1h, W1l, b1, pair_token, offsets, h_hi, h_lo, rb);
    k_ffn2<<<dim3(rows / 64, D_MOD / 256, D_FF / 512), dim3(256), 0, stream>>>(
        h_hi, h_lo, W2h, W2l, pair_token, pair_gate, offsets, out, rb);
  }
}

// Round 4
// 446.337 us; speedup vs baseline: 1.0449x; 1.0449x over previous
//
#include <hip/hip_runtime.h>

// MoE top-2 FFN, split-bf16 MFMA. Round 4:
//  - m97 recipe: SINGLE-buffered small LDS (24KB), 2 barriers/kstep, 5-6 blocks/CU
//  - 64-row tiles both GEMMs; grid ~2304 blocks -> ~18 waves/CU
//  - XCD-aware 1D grid linearization for panel L2 reuse (T1, m204 bijective)
//  - f-chunk loop (adaptive to ws_size) instead of row-chunk loop

#define T_TOKENS 4096
#define D_MOD 512
#define N_EXP 8
#define D_FF 2048
#define TPAD 128
#define P_CAP 9216       // 72*128 >= 8192 + 8*127

typedef __attribute__((ext_vector_type(4))) float f32x4_t;
typedef __attribute__((ext_vector_type(8))) short sh8;
typedef __attribute__((ext_vector_type(4))) unsigned short us4;

__device__ __forceinline__ unsigned short f2bh(float f) {
  unsigned u = __float_as_uint(f);
  return (unsigned short)((u + 0x7FFFu + ((u >> 16) & 1u)) >> 16);  // RNE
}
__device__ __forceinline__ float bh2f(unsigned short h) {
  return __uint_as_float(((unsigned)h) << 16);
}
__device__ __forceinline__ void gl_lds16(const void* g, void* l) {
  __builtin_amdgcn_global_load_lds(
      (const __attribute__((address_space(1))) unsigned int*)g,
      (__attribute__((address_space(3))) unsigned int*)l, 16, 0, 0);
}
// m204 bijective XCD swizzle: launched bid -> logical wg, per-XCD contiguous chunks
__device__ __forceinline__ int xcd_swz(int orig, int nwg) {
  int q = nwg >> 3, r = nwg & 7, x = orig & 7, w = orig >> 3;
  return (x < r ? x * (q + 1) : r * (q + 1) + (x - r) * q) + w;
}

// ---------------- routing ----------------

__global__ void k_init(int* counts, int* pair_token, float* pair_gate) {
  int idx = blockIdx.x * 256 + threadIdx.x;
  if (idx < P_CAP) { pair_token[idx] = -1; pair_gate[idx] = 0.f; }
  if (idx < N_EXP) counts[idx] = 0;
}

__global__ __launch_bounds__(256) void k_prep(const float* __restrict__ x,
    unsigned short* __restrict__ xh, unsigned short* __restrict__ xl) {
  int i = (blockIdx.x * 256 + threadIdx.x) * 8;
  float4 a = *(const float4*)(x + i);
  float4 b = *(const float4*)(x + i + 4);
  us4 h0 = {f2bh(a.x), f2bh(a.y), f2bh(a.z), f2bh(a.w)};
  us4 h1 = {f2bh(b.x), f2bh(b.y), f2bh(b.z), f2bh(b.w)};
  us4 l0 = {f2bh(a.x - bh2f(h0.x)), f2bh(a.y - bh2f(h0.y)),
            f2bh(a.z - bh2f(h0.z)), f2bh(a.w - bh2f(h0.w))};
  us4 l1 = {f2bh(b.x - bh2f(h1.x)), f2bh(b.y - bh2f(h1.y)),
            f2bh(b.z - bh2f(h1.z)), f2bh(b.w - bh2f(h1.w))};
  *(us4*)(xh + i) = h0; *(us4*)(xh + i + 4) = h1;
  *(us4*)(xl + i) = l0; *(us4*)(xl + i + 4) = l1;
}

__global__ __launch_bounds__(256) void k_gate(const float* __restrict__ x,
    const float* __restrict__ Wg, const float* __restrict__ bg,
    int* __restrict__ top_i, float* __restrict__ gates, int* __restrict__ counts) {
  __shared__ float wg_s[D_MOD * N_EXP];
  int tid = threadIdx.x;
  for (int i = tid; i < D_MOD * N_EXP; i += 256)
    wg_s[(i & 7) * D_MOD + (i >> 3)] = Wg[i];
  __syncthreads();
  int lane = tid & 63, w = tid >> 6;
  int t = blockIdx.x * 4 + w;
  const float* xr = x + (size_t)t * D_MOD;
  float acc[8];
#pragma unroll
  for (int e = 0; e < 8; ++e) acc[e] = 0.f;
#pragma unroll
  for (int it = 0; it < 2; ++it) {
    int d = it * 256 + lane * 4;
    float4 xv = *(const float4*)(xr + d);
#pragma unroll
    for (int e = 0; e < 8; ++e) {
      float4 wv = *(const float4*)(wg_s + e * D_MOD + d);
      acc[e] += xv.x * wv.x + xv.y * wv.y + xv.z * wv.z + xv.w * wv.w;
    }
  }
#pragma unroll
  for (int m = 32; m >= 1; m >>= 1)
#pragma unroll
    for (int e = 0; e < 8; ++e) acc[e] += __shfl_xor(acc[e], m);
  if (lane == 0) {
#pragma unroll
    for (int e = 0; e < 8; ++e) acc[e] += bg[e];
    int e0 = 0; float m0 = acc[0];
#pragma unroll
    for (int e = 1; e < 8; ++e) if (acc[e] > m0) { m0 = acc[e]; e0 = e; }
    int e1 = -1; float m1 = -3.4e38f;
#pragma unroll
    for (int e = 0; e < 8; ++e) if (e != e0 && acc[e] > m1) { m1 = acc[e]; e1 = e; }
    float g0 = 1.f / (1.f + __expf(m1 - m0));
    float g1 = 1.f - g0;
    top_i[t * 2] = e0; top_i[t * 2 + 1] = e1;
    gates[t * 2] = g0; gates[t * 2 + 1] = g1;
    atomicAdd(&counts[e0], 1);
    atomicAdd(&counts[e1], 1);
  }
}

__global__ void k_scan(const int* counts, int* offsets, int* cursor) {
  if (threadIdx.x == 0 && blockIdx.x == 0) {
    int o = 0;
    for (int e = 0; e < N_EXP; ++e) {
      offsets[e] = o; cursor[e] = o;
      o += (counts[e] + TPAD - 1) & ~(TPAD - 1);
    }
    offsets[N_EXP] = o;
  }
}

__global__ void k_scatter(const int* top_i, const float* gates, int* cursor,
                          int* pair_token, float* pair_gate) {
  int t = blockIdx.x * 256 + threadIdx.x;
#pragma unroll
  for (int k = 0; k < 2; ++k) {
    int e = top_i[t * 2 + k];
    int pos = atomicAdd(&cursor[e], 1);
    pair_token[pos] = t;
    pair_gate[pos] = gates[t * 2 + k];
  }
}

__global__ void k_outinit(const int* __restrict__ top_i, const float* __restrict__ gates,
                          const float* __restrict__ b2, float* __restrict__ out) {
  int idx = blockIdx.x * 256 + threadIdx.x;
  int t = idx >> 9, d = idx & 511;
  out[idx] = gates[t * 2] * b2[top_i[t * 2] * D_MOD + d] +
             gates[t * 2 + 1] * b2[top_i[t * 2 + 1] * D_MOD + d];
}

// -------- weight transpose + hi/lo split: W[e][R][C] -> Wt[e][C][R] --------

__global__ __launch_bounds__(256) void k_transpose(const float* __restrict__ W,
    unsigned short* __restrict__ Wh, unsigned short* __restrict__ Wl, int R, int C) {
  __shared__ float tile[32][33];
  int e = blockIdx.z;
  int c0 = blockIdx.x * 32, r0 = blockIdx.y * 32;
  const float* src = W + (size_t)e * R * C;
  int tx = threadIdx.x & 31, ty = threadIdx.x >> 5;
#pragma unroll
  for (int i = 0; i < 4; ++i) {
    int r = ty + i * 8;
    tile[r][tx] = src[(size_t)(r0 + r) * C + c0 + tx];
  }
  __syncthreads();
  int cl = threadIdx.x >> 3;
  int r4 = (threadIdx.x & 7) * 4;
  float v0 = tile[r4 + 0][cl], v1 = tile[r4 + 1][cl];
  float v2 = tile[r4 + 2][cl], v3 = tile[r4 + 3][cl];
  us4 hv = {f2bh(v0), f2bh(v1), f2bh(v2), f2bh(v3)};
  us4 lv = {f2bh(v0 - bh2f(hv.x)), f2bh(v1 - bh2f(hv.y)),
            f2bh(v2 - bh2f(hv.z)), f2bh(v3 - bh2f(hv.w))};
  size_t o = ((size_t)e * C + c0 + cl) * R + r0 + r4;
  *(us4*)(Wh + o) = hv;
  *(us4*)(Wl + o) = lv;
}

// -------- GEMM1: h = relu(x @ W1 + b1), 64x128 tile, 4 waves, single-buf BK=32 --------
// LDS row: 128B = [hi 64B | lo 64B]; slot s (16B) holds source chunk s^(row&7).

__global__ __launch_bounds__(256) void k_ffn1(
    const unsigned short* __restrict__ xh, const unsigned short* __restrict__ xl,
    const unsigned short* __restrict__ W1h, const unsigned short* __restrict__ W1l,
    const float* __restrict__ b1, const int* __restrict__ pair_token,
    const int* __restrict__ offsets, unsigned short* __restrict__ h_hi,
    unsigned short* __restrict__ h_lo, int fb, int FC) {
  int FT = FC >> 7;
  int wg = xcd_swz(blockIdx.x, gridDim.x);
  int rb = wg / FT, fi = wg - rb * FT;      // rb-major: x-panel L2 reuse across fi
  int total = offsets[N_EXP];
  int row0 = rb * 64;
  if (row0 >= total) return;
  int f0 = fb + fi * 128;
  int e = 0;
  while (offsets[e + 1] <= row0) ++e;

  __shared__ __align__(16) char lds[24576];   // A 8KB + B 16KB, single buffer
  char* Ad = lds;
  char* Bd = lds + 8192;
  int tid = threadIdx.x;

  int s = tid & 7, rq = tid >> 3;             // rq 0..31
  int c = s ^ (rq & 7);
  const unsigned short* bA = (c < 4) ? xh : xl;
  const unsigned short* bB = (c < 4) ? W1h : W1l;
  size_t wb = (size_t)e * D_FF * D_MOD;
  const char* srcA[2]; const char* srcB[4];
#pragma unroll
  for (int i = 0; i < 2; ++i) {
    int t_ = pair_token[row0 + rq + i * 32];
    if (t_ < 0) t_ = 0;
    srcA[i] = (const char*)(bA + (size_t)t_ * D_MOD + (c & 3) * 8);
  }
#pragma unroll
  for (int i = 0; i < 4; ++i)
    srcB[i] = (const char*)(bB + wb + (size_t)(f0 + rq + i * 32) * D_MOD + (c & 3) * 8);

  int lane = tid & 63, wid = tid >> 6;
  int wr = wid & 1, wc = wid >> 1;            // 2x2 waves, wave tile 32x64
  int lrow = lane & 15, kblk = lane >> 4;
  const f32x4_t zero = {0.f, 0.f, 0.f, 0.f};
  f32x4_t acc[2][4];
#pragma unroll
  for (int a = 0; a < 2; ++a)
#pragma unroll
    for (int b = 0; b < 4; ++b) acc[a][b] = zero;

  for (int ks = 0; ks < 16; ++ks) {
    int kb = ks * 64;                         // 32 elems * 2B
    __syncthreads();                          // prev reads done before overwrite
#pragma unroll
    for (int i = 0; i < 2; ++i) gl_lds16(srcA[i] + kb, Ad + tid * 16 + i * 4096);
#pragma unroll
    for (int i = 0; i < 4; ++i) gl_lds16(srcB[i] + kb, Bd + tid * 16 + i * 4096);
    __syncthreads();                          // staged data visible
    sh8 ah[2], al[2], bh[4], bl[4];
#pragma unroll
    for (int rt = 0; rt < 2; ++rt) {
      int row = wr * 32 + rt * 16 + lrow;
      int base = row * 128;
      ah[rt] = *(const sh8*)(Ad + base + ((kblk ^ (row & 7)) << 4));
      al[rt] = *(const sh8*)(Ad + base + (((kblk + 4) ^ (row & 7)) << 4));
    }
#pragma unroll
    for (int ct = 0; ct < 4; ++ct) {
      int row = wc * 64 + ct * 16 + lrow;
      int base = row * 128;
      bh[ct] = *(const sh8*)(Bd + base + ((kblk ^ (row & 7)) << 4));
      bl[ct] = *(const sh8*)(Bd + base + (((kblk + 4) ^ (row & 7)) << 4));
    }
#pragma unroll
    for (int rt = 0; rt < 2; ++rt)
#pragma unroll
      for (int ct = 0; ct < 4; ++ct) {
        acc[rt][ct] = __builtin_amdgcn_mfma_f32_16x16x32_bf16(ah[rt], bh[ct], acc[rt][ct], 0, 0, 0);
        acc[rt][ct] = __builtin_amdgcn_mfma_f32_16x16x32_bf16(ah[rt], bl[ct], acc[rt][ct], 0, 0, 0);
        acc[rt][ct] = __builtin_amdgcn_mfma_f32_16x16x32_bf16(al[rt], bh[ct], acc[rt][ct], 0, 0, 0);
      }
  }

  // epilogue: relu(+b1), split hi/lo, vectorized store via 16KB LDS scratch
  float b1v[4];
#pragma unroll
  for (int ct = 0; ct < 4; ++ct)
    b1v[ct] = b1[e * D_FF + f0 + wc * 64 + ct * 16 + lrow];
  float* hs = (float*)lds;                    // 64 x 64 f32 = 16KB
#pragma unroll
  for (int hf = 0; hf < 2; ++hf) {
    __syncthreads();
    if (wc == hf) {
#pragma unroll
      for (int rt = 0; rt < 2; ++rt)
#pragma unroll
        for (int ct = 0; ct < 4; ++ct)
#pragma unroll
          for (int j = 0; j < 4; ++j) {
            int row = wr * 32 + rt * 16 + kblk * 4 + j;   // C/D: row=(l>>4)*4+reg
            int col = ct * 16 + lrow;                     // col = l&15
            float v = fmaxf(acc[rt][ct][j] + b1v[ct], 0.f);
            int c4 = col >> 2;
            hs[row * 64 + ((c4 ^ ((row & 3) << 2)) << 2) + (col & 3)] = v;
          }
    }
    __syncthreads();
#pragma unroll
    for (int i = 0; i < 4; ++i) {
      int idx = tid + i * 256;                // 1024 float4 = 64 rows x 16
      int r = idx >> 4, c4 = idx & 15;
      float4 v = *(const float4*)(hs + r * 64 + ((c4 ^ ((r & 3) << 2)) << 2));
      us4 hv = {f2bh(v.x), f2bh(v.y), f2bh(v.z), f2bh(v.w)};
      us4 lv = {f2bh(v.x - bh2f(hv.x)), f2bh(v.y - bh2f(hv.y)),
                f2bh(v.z - bh2f(hv.z)), f2bh(v.w - bh2f(hv.w))};
      size_t o = (size_t)(row0 + r) * FC + fi * 128 + hf * 64 + c4 * 4;
      *(us4*)(h_hi + o) = hv;
      *(us4*)(h_lo + o) = lv;
    }
  }
}

// -------- GEMM2: out += gate * (h @ W2), 64x128 tile, 4 waves, single-buf BK=32 --------

__global__ __launch_bounds__(256) void k_ffn2(
    const unsigned short* __restrict__ h_hi, const unsigned short* __restrict__ h_lo,
    const unsigned short* __restrict__ W2h, const unsigned short* __restrict__ W2l,
    const int* __restrict__ pair_token, const float* __restrict__ pair_gate,
    const int* __restrict__ offsets, float* __restrict__ out, int fb, int FC,
    int RB2) {
  int wg = xcd_swz(blockIdx.x, gridDim.x);
  int nblk = wg & 3;                          // n fastest: h A-panel shared per XCD
  int tmp = wg >> 2;
  int rb = tmp % RB2, z = tmp / RB2;
  int total = offsets[N_EXP];
  int row0 = rb * 64;
  if (row0 >= total) return;
  int n0 = nblk * 128;
  int kc = z * 512;                           // local k within f-chunk
  int Kloc = (FC < 512) ? FC : 512;
  int e = 0;
  while (offsets[e + 1] <= row0) ++e;

  __shared__ __align__(16) char lds[24576];   // A 8KB + B 16KB, single buffer
  char* Ad = lds;
  char* Bd = lds + 8192;
  int tid = threadIdx.x;

  int s = tid & 7, rq = tid >> 3;
  int c = s ^ (rq & 7);
  const unsigned short* bA = (c < 4) ? h_hi : h_lo;
  const unsigned short* bB = (c < 4) ? W2h : W2l;
  size_t wb = (size_t)e * D_MOD * D_FF;
  const char* srcA[2]; const char* srcB[4];
#pragma unroll
  for (int i = 0; i < 2; ++i)
    srcA[i] = (const char*)(bA + (size_t)(row0 + rq + i * 32) * FC + kc + (c & 3) * 8);
#pragma unroll
  for (int i = 0; i < 4; ++i)
    srcB[i] = (const char*)(bB + wb + (size_t)(n0 + rq + i * 32) * D_FF + fb + kc + (c & 3) * 8);

  int lane = tid & 63, wc = tid >> 6;         // 1x4 waves, wave tile 64x32
  int lrow = lane & 15, kblk = lane >> 4;
  const f32x4_t zero = {0.f, 0.f, 0.f, 0.f};
  f32x4_t acc[4][2];
#pragma unroll
  for (int a = 0; a < 4; ++a)
#pragma unroll
    for (int b = 0; b < 2; ++b) acc[a][b] = zero;

  int nsteps = Kloc / 32;
  for (int ks = 0; ks < nsteps; ++ks) {
    int kb = ks * 64;
    __syncthreads();
#pragma unroll
    for (int i = 0; i < 2; ++i) gl_lds16(srcA[i] + kb, Ad + tid * 16 + i * 4096);
#pragma unroll
    for (int i = 0; i < 4; ++i) gl_lds16(srcB[i] + kb, Bd + tid * 16 + i * 4096);
    __syncthreads();
    sh8 ah[4], al[4], bh[2], bl[2];
#pragma unroll
    for (int rt = 0; rt < 4; ++rt) {
      int row = rt * 16 + lrow;
      int base = row * 128;
      ah[rt] = *(const sh8*)(Ad + base + ((kblk ^ (row & 7)) << 4));
      al[rt] = *(const sh8*)(Ad + base + (((kblk + 4) ^ (row & 7)) << 4));
    }
#pragma unroll
    for (int ct = 0; ct < 2; ++ct) {
      int row = wc * 32 + ct * 16 + lrow;
      int base = row * 128;
      bh[ct] = *(const sh8*)(Bd + base + ((kblk ^ (row & 7)) << 4));
      bl[ct] = *(const sh8*)(Bd + base + (((kblk + 4) ^ (row & 7)) << 4));
    }
#pragma unroll
    for (int rt = 0; rt < 4; ++rt)
#pragma unroll
      for (int ct = 0; ct < 2; ++ct) {
        acc[rt][ct] = __builtin_amdgcn_mfma_f32_16x16x32_bf16(ah[rt], bh[ct], acc[rt][ct], 0, 0, 0);
        acc[rt][ct] = __builtin_amdgcn_mfma_f32_16x16x32_bf16(ah[rt], bl[ct], acc[rt][ct], 0, 0, 0);
        acc[rt][ct] = __builtin_amdgcn_mfma_f32_16x16x32_bf16(al[rt], bh[ct], acc[rt][ct], 0, 0, 0);
      }
  }

#pragma unroll
  for (int rt = 0; rt < 4; ++rt)
#pragma unroll
    for (int j = 0; j < 4; ++j) {
      int row = rt * 16 + kblk * 4 + j;
      int t_ = pair_token[row0 + row];
      if (t_ >= 0) {
        float g = pair_gate[row0 + row];
#pragma unroll
        for (int ct = 0; ct < 2; ++ct) {
          int n = n0 + wc * 32 + ct * 16 + lrow;
          atomicAdd(out + (size_t)t_ * D_MOD + n, g * acc[rt][ct][j]);
        }
      }
    }
}

// ---------------- launch ----------------

extern "C" void kernel_launch(void* const* d_in, const int* in_sizes, int n_in,
                              void* d_out, int out_size, void* d_ws, size_t ws_size,
                              hipStream_t stream) {
  const float* x  = (const float*)d_in[0];
  const float* Wg = (const float*)d_in[1];
  const float* bg = (const float*)d_in[2];
  const float* W1 = (const float*)d_in[3];
  const float* b1 = (const float*)d_in[4];
  const float* W2 = (const float*)d_in[5];
  const float* b2 = (const float*)d_in[6];
  float* out = (float*)d_out;

  char* ws = (char*)d_ws;
  size_t off = 0;
  auto take = [&](size_t bytes) -> char* {
    char* p = ws + off;
    off += (bytes + 255) & ~(size_t)255;
    return p;
  };
  const size_t WELEMS = (size_t)N_EXP * D_MOD * D_FF;
  unsigned short* W1h = (unsigned short*)take(WELEMS * 2);
  unsigned short* W1l = (unsigned short*)take(WELEMS * 2);
  unsigned short* W2h = (unsigned short*)take(WELEMS * 2);
  unsigned short* W2l = (unsigned short*)take(WELEMS * 2);
  unsigned short* xh  = (unsigned short*)take((size_t)T_TOKENS * D_MOD * 2);
  unsigned short* xl  = (unsigned short*)take((size_t)T_TOKENS * D_MOD * 2);
  int*   top_i      = (int*)take((size_t)T_TOKENS * 2 * 4);
  float* gates      = (float*)take((size_t)T_TOKENS * 2 * 4);
  int*   counts     = (int*)take(64);
  int*   offsets    = (int*)take(64);
  int*   cursor     = (int*)take(64);
  int*   pair_token = (int*)take((size_t)P_CAP * 4);
  float* pair_gate  = (float*)take((size_t)P_CAP * 4);

  // pick largest f-chunk whose h hi/lo buffers fit the remaining workspace
  size_t h_avail = (ws_size > off) ? ws_size - off : 0;
  int FC = 2048;
  while (FC > 256 && (size_t)P_CAP * FC * 4 > h_avail) FC >>= 1;
  unsigned short* h_hi = (unsigned short*)(ws + off);
  unsigned short* h_lo = h_hi + (size_t)P_CAP * FC;

  k_init<<<dim3((P_CAP + 255) / 256), dim3(256), 0, stream>>>(counts, pair_token, pair_gate);
  k_prep<<<dim3(T_TOKENS * D_MOD / 2048), dim3(256), 0, stream>>>(x, xh, xl);
  k_gate<<<dim3(T_TOKENS / 4), dim3(256), 0, stream>>>(x, Wg, bg, top_i, gates, counts);
  k_scan<<<dim3(1), dim3(64), 0, stream>>>(counts, offsets, cursor);
  k_scatter<<<dim3(T_TOKENS / 256), dim3(256), 0, stream>>>(top_i, gates, cursor, pair_token, pair_gate);
  k_outinit<<<dim3(T_TOKENS * D_MOD / 256), dim3(256), 0, stream>>>(top_i, gates, b2, out);
  k_transpose<<<dim3(D_FF / 32, D_MOD / 32, N_EXP), dim3(256), 0, stream>>>(W1, W1h, W1l, D_MOD, D_FF);
  k_transpose<<<dim3(D_MOD / 32, D_FF / 32, N_EXP), dim3(256), 0, stream>>>(W2, W2h, W2l, D_FF, D_MOD);

  const int RB1 = P_CAP / 64;   // 144
  const int RB2 = P_CAP / 64;   // 144
  int KS = (FC >= 512) ? FC / 512 : 1;
  for (int fb = 0; fb < D_FF; fb += FC) {
    k_ffn1<<<dim3(RB1 * (FC / 128)), dim3(256), 0, stream>>>(
        xh, xl, W1h, W1l, b1, pair_token, offsets, h_hi, h_lo, fb, FC);
    k_ffn2<<<dim3(RB2 * 4 * KS), dim3(256), 0, stream>>>(
        h_hi, h_lo, W2h, W2l, pair_token, pair_gate, offsets, out, fb, FC, RB2);
  }
}

// Round 5
// 430.503 us; speedup vs baseline: 1.0833x; 1.0368x over previous
//
#include <hip/hip_runtime.h>

// MoE top-2 FFN, split-bf16 MFMA. Round 5:
//  - NO output atomics: ffn2 writes per-pair y rows; k_combine gathers via pair_pos
//  - ffn1 128x128 tile (m97 shape, 48 MFMA : 16 ds_read, 32KB LDS)
//  - ffn2 64x128 tile, full K=2048 per block (no k-split), 576 blocks all-resident
//  - fewer dispatches: prep(+counts), gate, scan(+pair init), scatter, 2x transpose,
//    ffn1, ffn2, combine

#define T_TOKENS 4096
#define D_MOD 512
#define N_EXP 8
#define D_FF 2048
#define TPAD 128
#define P_CAP 9216       // 72*128 >= 8192 + 8*127

typedef __attribute__((ext_vector_type(4))) float f32x4_t;
typedef __attribute__((ext_vector_type(8))) short sh8;
typedef __attribute__((ext_vector_type(4))) unsigned short us4;

__device__ __forceinline__ unsigned short f2bh(float f) {
  unsigned u = __float_as_uint(f);
  return (unsigned short)((u + 0x7FFFu + ((u >> 16) & 1u)) >> 16);  // RNE
}
__device__ __forceinline__ float bh2f(unsigned short h) {
  return __uint_as_float(((unsigned)h) << 16);
}
__device__ __forceinline__ void gl_lds16(const void* g, void* l) {
  __builtin_amdgcn_global_load_lds(
      (const __attribute__((address_space(1))) unsigned int*)g,
      (__attribute__((address_space(3))) unsigned int*)l, 16, 0, 0);
}
__device__ __forceinline__ int xcd_swz(int orig, int nwg) {
  int q = nwg >> 3, r = nwg & 7, x = orig & 7, w = orig >> 3;
  return (x < r ? x * (q + 1) : r * (q + 1) + (x - r) * q) + w;
}

// ---------------- routing / prep ----------------

__global__ __launch_bounds__(256) void k_prep(const float* __restrict__ x,
    unsigned short* __restrict__ xh, unsigned short* __restrict__ xl,
    int* __restrict__ counts) {
  if (blockIdx.x == 0 && threadIdx.x < N_EXP) counts[threadIdx.x] = 0;
  int i = (blockIdx.x * 256 + threadIdx.x) * 8;
  float4 a = *(const float4*)(x + i);
  float4 b = *(const float4*)(x + i + 4);
  us4 h0 = {f2bh(a.x), f2bh(a.y), f2bh(a.z), f2bh(a.w)};
  us4 h1 = {f2bh(b.x), f2bh(b.y), f2bh(b.z), f2bh(b.w)};
  us4 l0 = {f2bh(a.x - bh2f(h0.x)), f2bh(a.y - bh2f(h0.y)),
            f2bh(a.z - bh2f(h0.z)), f2bh(a.w - bh2f(h0.w))};
  us4 l1 = {f2bh(b.x - bh2f(h1.x)), f2bh(b.y - bh2f(h1.y)),
            f2bh(b.z - bh2f(h1.z)), f2bh(b.w - bh2f(h1.w))};
  *(us4*)(xh + i) = h0; *(us4*)(xh + i + 4) = h1;
  *(us4*)(xl + i) = l0; *(us4*)(xl + i + 4) = l1;
}

__global__ __launch_bounds__(256) void k_gate(const float* __restrict__ x,
    const float* __restrict__ Wg, const float* __restrict__ bg,
    int* __restrict__ top_i, float* __restrict__ gates, int* __restrict__ counts) {
  __shared__ float wg_s[D_MOD * N_EXP];
  int tid = threadIdx.x;
  for (int i = tid; i < D_MOD * N_EXP; i += 256)
    wg_s[(i & 7) * D_MOD + (i >> 3)] = Wg[i];
  __syncthreads();
  int lane = tid & 63, w = tid >> 6;
  int t = blockIdx.x * 4 + w;
  const float* xr = x + (size_t)t * D_MOD;
  float acc[8];
#pragma unroll
  for (int e = 0; e < 8; ++e) acc[e] = 0.f;
#pragma unroll
  for (int it = 0; it < 2; ++it) {
    int d = it * 256 + lane * 4;
    float4 xv = *(const float4*)(xr + d);
#pragma unroll
    for (int e = 0; e < 8; ++e) {
      float4 wv = *(const float4*)(wg_s + e * D_MOD + d);
      acc[e] += xv.x * wv.x + xv.y * wv.y + xv.z * wv.z + xv.w * wv.w;
    }
  }
#pragma unroll
  for (int m = 32; m >= 1; m >>= 1)
#pragma unroll
    for (int e = 0; e < 8; ++e) acc[e] += __shfl_xor(acc[e], m);
  if (lane == 0) {
#pragma unroll
    for (int e = 0; e < 8; ++e) acc[e] += bg[e];
    int e0 = 0; float m0 = acc[0];
#pragma unroll
    for (int e = 1; e < 8; ++e) if (acc[e] > m0) { m0 = acc[e]; e0 = e; }
    int e1 = -1; float m1 = -3.4e38f;
#pragma unroll
    for (int e = 0; e < 8; ++e) if (e != e0 && acc[e] > m1) { m1 = acc[e]; e1 = e; }
    float g0 = 1.f / (1.f + __expf(m1 - m0));
    float g1 = 1.f - g0;
    top_i[t * 2] = e0; top_i[t * 2 + 1] = e1;
    gates[t * 2] = g0; gates[t * 2 + 1] = g1;
    atomicAdd(&counts[e0], 1);
    atomicAdd(&counts[e1], 1);
  }
}

__global__ void k_scan(const int* counts, int* offsets, int* cursor,
                       int* pair_token) {
  if (threadIdx.x == 0) {
    int o = 0;
    for (int e = 0; e < N_EXP; ++e) {
      offsets[e] = o; cursor[e] = o;
      o += (counts[e] + TPAD - 1) & ~(TPAD - 1);
    }
    offsets[N_EXP] = o;
  }
  for (int i = threadIdx.x; i < P_CAP; i += 256) pair_token[i] = -1;
}

__global__ void k_scatter(const int* top_i, int* cursor,
                          int* pair_token, int* pair_pos) {
  int t = blockIdx.x * 256 + threadIdx.x;
#pragma unroll
  for (int k = 0; k < 2; ++k) {
    int e = top_i[t * 2 + k];
    int pos = atomicAdd(&cursor[e], 1);
    pair_token[pos] = t;
    pair_pos[t * 2 + k] = pos;
  }
}

// -------- weight transpose + hi/lo split: W[e][R][C] -> Wt[e][C][R] --------

__global__ __launch_bounds__(256) void k_transpose(const float* __restrict__ W,
    unsigned short* __restrict__ Wh, unsigned short* __restrict__ Wl, int R, int C) {
  __shared__ float tile[32][33];
  int e = blockIdx.z;
  int c0 = blockIdx.x * 32, r0 = blockIdx.y * 32;
  const float* src = W + (size_t)e * R * C;
  int tx = threadIdx.x & 31, ty = threadIdx.x >> 5;
#pragma unroll
  for (int i = 0; i < 4; ++i) {
    int r = ty + i * 8;
    tile[r][tx] = src[(size_t)(r0 + r) * C + c0 + tx];
  }
  __syncthreads();
  int cl = threadIdx.x >> 3;
  int r4 = (threadIdx.x & 7) * 4;
  float v0 = tile[r4 + 0][cl], v1 = tile[r4 + 1][cl];
  float v2 = tile[r4 + 2][cl], v3 = tile[r4 + 3][cl];
  us4 hv = {f2bh(v0), f2bh(v1), f2bh(v2), f2bh(v3)};
  us4 lv = {f2bh(v0 - bh2f(hv.x)), f2bh(v1 - bh2f(hv.y)),
            f2bh(v2 - bh2f(hv.z)), f2bh(v3 - bh2f(hv.w))};
  size_t o = ((size_t)e * C + c0 + cl) * R + r0 + r4;
  *(us4*)(Wh + o) = hv;
  *(us4*)(Wl + o) = lv;
}

// -------- GEMM1: h = relu(x @ W1 + b1), 128x128 tile, 4 waves, single-buf BK=32 --------
// LDS row: 128B = [hi 64B | lo 64B]; 16B slot s holds source chunk s^(row&7).

__global__ __launch_bounds__(256) void k_ffn1(
    const unsigned short* __restrict__ xh, const unsigned short* __restrict__ xl,
    const unsigned short* __restrict__ W1h, const unsigned short* __restrict__ W1l,
    const float* __restrict__ b1, const int* __restrict__ pair_token,
    const int* __restrict__ offsets, unsigned short* __restrict__ h_hi,
    unsigned short* __restrict__ h_lo, int rbase) {
  int wg = xcd_swz(blockIdx.x, gridDim.x);
  int rb = wg >> 4, fi = wg & 15;           // rb-major: x panel L2 reuse across fi
  int row0 = rbase + rb * 128;
  int total = offsets[N_EXP];
  if (row0 >= total) return;
  int f0 = fi * 128;
  int e = 0;
  while (offsets[e + 1] <= row0) ++e;

  __shared__ __align__(16) char lds[32768];   // A 16KB + B 16KB
  char* Ad = lds;
  char* Bd = lds + 16384;
  int tid = threadIdx.x;

  int s = tid & 7, rq = tid >> 3;             // rq 0..31
  int c = s ^ (rq & 7);
  const unsigned short* bA = (c < 4) ? xh : xl;
  const unsigned short* bB = (c < 4) ? W1h : W1l;
  size_t wb = (size_t)e * D_FF * D_MOD;
  const char* srcA[4]; const char* srcB[4];
#pragma unroll
  for (int i = 0; i < 4; ++i) {
    int t_ = pair_token[row0 + rq + i * 32];
    if (t_ < 0) t_ = 0;
    srcA[i] = (const char*)(bA + (size_t)t_ * D_MOD + (c & 3) * 8);
    srcB[i] = (const char*)(bB + wb + (size_t)(f0 + rq + i * 32) * D_MOD + (c & 3) * 8);
  }

  int lane = tid & 63, wid = tid >> 6;
  int wr = wid & 1, wc = wid >> 1;            // 2x2 waves, wave tile 64x64
  int lrow = lane & 15, kblk = lane >> 4;
  const f32x4_t zero = {0.f, 0.f, 0.f, 0.f};
  f32x4_t acc[4][4];
#pragma unroll
  for (int a = 0; a < 4; ++a)
#pragma unroll
    for (int b = 0; b < 4; ++b) acc[a][b] = zero;

  for (int ks = 0; ks < 16; ++ks) {
    int kb = ks * 64;                         // 32 elems * 2B
    __syncthreads();
#pragma unroll
    for (int i = 0; i < 4; ++i) gl_lds16(srcA[i] + kb, Ad + tid * 16 + i * 4096);
#pragma unroll
    for (int i = 0; i < 4; ++i) gl_lds16(srcB[i] + kb, Bd + tid * 16 + i * 4096);
    __syncthreads();
    sh8 ah[4], al[4], bh[4], bl[4];
#pragma unroll
    for (int rt = 0; rt < 4; ++rt) {
      int row = wr * 64 + rt * 16 + lrow;
      int base = row * 128;
      ah[rt] = *(const sh8*)(Ad + base + ((kblk ^ (row & 7)) << 4));
      al[rt] = *(const sh8*)(Ad + base + (((kblk + 4) ^ (row & 7)) << 4));
    }
#pragma unroll
    for (int ct = 0; ct < 4; ++ct) {
      int row = wc * 64 + ct * 16 + lrow;
      int base = row * 128;
      bh[ct] = *(const sh8*)(Bd + base + ((kblk ^ (row & 7)) << 4));
      bl[ct] = *(const sh8*)(Bd + base + (((kblk + 4) ^ (row & 7)) << 4));
    }
#pragma unroll
    for (int rt = 0; rt < 4; ++rt)
#pragma unroll
      for (int ct = 0; ct < 4; ++ct) {
        acc[rt][ct] = __builtin_amdgcn_mfma_f32_16x16x32_bf16(ah[rt], bh[ct], acc[rt][ct], 0, 0, 0);
        acc[rt][ct] = __builtin_amdgcn_mfma_f32_16x16x32_bf16(ah[rt], bl[ct], acc[rt][ct], 0, 0, 0);
        acc[rt][ct] = __builtin_amdgcn_mfma_f32_16x16x32_bf16(al[rt], bh[ct], acc[rt][ct], 0, 0, 0);
      }
  }

  // epilogue: relu(+b1), hi/lo split, vectorized store via 32KB LDS (two col halves)
  float b1v[4];
#pragma unroll
  for (int ct = 0; ct < 4; ++ct)
    b1v[ct] = b1[e * D_FF + f0 + wc * 64 + ct * 16 + lrow];
  int crow = row0 - rbase;
  float* hs = (float*)lds;                    // 128 x 64 f32 = 32KB
#pragma unroll
  for (int hf = 0; hf < 2; ++hf) {
    __syncthreads();
    if (wc == hf) {
#pragma unroll
      for (int rt = 0; rt < 4; ++rt)
#pragma unroll
        for (int ct = 0; ct < 4; ++ct)
#pragma unroll
          for (int j = 0; j < 4; ++j) {
            int row = wr * 64 + rt * 16 + kblk * 4 + j;   // C/D: row=(l>>4)*4+reg
            int col = ct * 16 + lrow;                     // col = l&15
            float v = fmaxf(acc[rt][ct][j] + b1v[ct], 0.f);
            int c4 = col >> 2;
            hs[row * 64 + ((c4 ^ ((row & 3) << 2)) << 2) + (col & 3)] = v;
          }
    }
    __syncthreads();
#pragma unroll
    for (int i = 0; i < 8; ++i) {
      int idx = tid + i * 256;                // 2048 float4 = 128 rows x 16
      int r = idx >> 4, c4 = idx & 15;
      float4 v = *(const float4*)(hs + r * 64 + ((c4 ^ ((r & 3) << 2)) << 2));
      us4 hv = {f2bh(v.x), f2bh(v.y), f2bh(v.z), f2bh(v.w)};
      us4 lv = {f2bh(v.x - bh2f(hv.x)), f2bh(v.y - bh2f(hv.y)),
                f2bh(v.z - bh2f(hv.z)), f2bh(v.w - bh2f(hv.w))};
      size_t o = (size_t)(crow + r) * D_FF + f0 + hf * 64 + c4 * 4;
      *(us4*)(h_hi + o) = hv;
      *(us4*)(h_lo + o) = lv;
    }
  }
}

// -------- GEMM2: y[pair] = h @ W2, 64x128 tile, full K=2048, NO atomics --------

__global__ __launch_bounds__(256) void k_ffn2(
    const unsigned short* __restrict__ h_hi, const unsigned short* __restrict__ h_lo,
    const unsigned short* __restrict__ W2h, const unsigned short* __restrict__ W2l,
    const int* __restrict__ offsets, float* __restrict__ y, int rbase) {
  int wg = xcd_swz(blockIdx.x, gridDim.x);
  int rb = wg >> 2, nblk = wg & 3;            // nblk fastest: h A-panel L2 reuse
  int row0 = rbase + rb * 64;
  int total = offsets[N_EXP];
  if (row0 >= total) return;
  int n0 = nblk * 128;
  int e = 0;
  while (offsets[e + 1] <= row0) ++e;

  __shared__ __align__(16) char lds[24576];   // A 8KB + B 16KB
  char* Ad = lds;
  char* Bd = lds + 8192;
  int tid = threadIdx.x;
  int crow = rb * 64;                         // h-buffer row (chunk-local)

  int s = tid & 7, rq = tid >> 3;
  int c = s ^ (rq & 7);
  const unsigned short* bA = (c < 4) ? h_hi : h_lo;
  const unsigned short* bB = (c < 4) ? W2h : W2l;
  size_t wb = (size_t)e * D_MOD * D_FF;
  const char* srcA[2]; const char* srcB[4];
#pragma unroll
  for (int i = 0; i < 2; ++i)
    srcA[i] = (const char*)(bA + (size_t)(crow + rq + i * 32) * D_FF + (c & 3) * 8);
#pragma unroll
  for (int i = 0; i < 4; ++i)
    srcB[i] = (const char*)(bB + wb + (size_t)(n0 + rq + i * 32) * D_FF + (c & 3) * 8);

  int lane = tid & 63, wc = tid >> 6;         // 1x4 waves, wave tile 64x32
  int lrow = lane & 15, kblk = lane >> 4;
  const f32x4_t zero = {0.f, 0.f, 0.f, 0.f};
  f32x4_t acc[4][2];
#pragma unroll
  for (int a = 0; a < 4; ++a)
#pragma unroll
    for (int b = 0; b < 2; ++b) acc[a][b] = zero;

  for (int ks = 0; ks < 64; ++ks) {
    int kb = ks * 64;
    __syncthreads();
#pragma unroll
    for (int i = 0; i < 2; ++i) gl_lds16(srcA[i] + kb, Ad + tid * 16 + i * 4096);
#pragma unroll
    for (int i = 0; i < 4; ++i) gl_lds16(srcB[i] + kb, Bd + tid * 16 + i * 4096);
    __syncthreads();
    sh8 ah[4], al[4], bh[2], bl[2];
#pragma unroll
    for (int rt = 0; rt < 4; ++rt) {
      int row = rt * 16 + lrow;
      int base = row * 128;
      ah[rt] = *(const sh8*)(Ad + base + ((kblk ^ (row & 7)) << 4));
      al[rt] = *(const sh8*)(Ad + base + (((kblk + 4) ^ (row & 7)) << 4));
    }
#pragma unroll
    for (int ct = 0; ct < 2; ++ct) {
      int row = wc * 32 + ct * 16 + lrow;
      int base = row * 128;
      bh[ct] = *(const sh8*)(Bd + base + ((kblk ^ (row & 7)) << 4));
      bl[ct] = *(const sh8*)(Bd + base + (((kblk + 4) ^ (row & 7)) << 4));
    }
#pragma unroll
    for (int rt = 0; rt < 4; ++rt)
#pragma unroll
      for (int ct = 0; ct < 2; ++ct) {
        acc[rt][ct] = __builtin_amdgcn_mfma_f32_16x16x32_bf16(ah[rt], bh[ct], acc[rt][ct], 0, 0, 0);
        acc[rt][ct] = __builtin_amdgcn_mfma_f32_16x16x32_bf16(ah[rt], bl[ct], acc[rt][ct], 0, 0, 0);
        acc[rt][ct] = __builtin_amdgcn_mfma_f32_16x16x32_bf16(al[rt], bh[ct], acc[rt][ct], 0, 0, 0);
      }
  }

  // epilogue: plain stores to per-pair y rows (each element written once)
#pragma unroll
  for (int rt = 0; rt < 4; ++rt)
#pragma unroll
    for (int j = 0; j < 4; ++j) {
      int row = rt * 16 + kblk * 4 + j;
#pragma unroll
      for (int ct = 0; ct < 2; ++ct) {
        int n = n0 + wc * 32 + ct * 16 + lrow;
        y[(size_t)(row0 + row) * D_MOD + n] = acc[rt][ct][j];
      }
    }
}

// -------- combine: out[t] = g0*(y[p0]+b2[e0]) + g1*(y[p1]+b2[e1]) --------

__global__ __launch_bounds__(256) void k_combine(const float* __restrict__ y,
    const int* __restrict__ pair_pos, const int* __restrict__ top_i,
    const float* __restrict__ gates, const float* __restrict__ b2,
    float* __restrict__ out) {
  int idx = blockIdx.x * 256 + threadIdx.x;   // 524288 float4 units
  int t = idx >> 7, q = (idx & 127) * 4;
  int p0 = pair_pos[t * 2], p1 = pair_pos[t * 2 + 1];
  float g0 = gates[t * 2], g1 = gates[t * 2 + 1];
  int e0 = top_i[t * 2], e1 = top_i[t * 2 + 1];
  float4 a = *(const float4*)(y + (size_t)p0 * D_MOD + q);
  float4 b = *(const float4*)(y + (size_t)p1 * D_MOD + q);
  float4 c0 = *(const float4*)(b2 + e0 * D_MOD + q);
  float4 c1 = *(const float4*)(b2 + e1 * D_MOD + q);
  float4 r;
  r.x = g0 * (a.x + c0.x) + g1 * (b.x + c1.x);
  r.y = g0 * (a.y + c0.y) + g1 * (b.y + c1.y);
  r.z = g0 * (a.z + c0.z) + g1 * (b.z + c1.z);
  r.w = g0 * (a.w + c0.w) + g1 * (b.w + c1.w);
  *(float4*)(out + (size_t)t * D_MOD + q) = r;
}

// ---------------- launch ----------------

extern "C" void kernel_launch(void* const* d_in, const int* in_sizes, int n_in,
                              void* d_out, int out_size, void* d_ws, size_t ws_size,
                              hipStream_t stream) {
  const float* x  = (const float*)d_in[0];
  const float* Wg = (const float*)d_in[1];
  const float* bg = (const float*)d_in[2];
  const float* W1 = (const float*)d_in[3];
  const float* b1 = (const float*)d_in[4];
  const float* W2 = (const float*)d_in[5];
  const float* b2 = (const float*)d_in[6];
  float* out = (float*)d_out;

  char* ws = (char*)d_ws;
  size_t off = 0;
  auto take = [&](size_t bytes) -> char* {
    char* p = ws + off;
    off += (bytes + 255) & ~(size_t)255;
    return p;
  };
  const size_t WELEMS = (size_t)N_EXP * D_MOD * D_FF;
  unsigned short* W1h = (unsigned short*)take(WELEMS * 2);
  unsigned short* W1l = (unsigned short*)take(WELEMS * 2);
  unsigned short* W2h = (unsigned short*)take(WELEMS * 2);
  unsigned short* W2l = (unsigned short*)take(WELEMS * 2);
  unsigned short* xh  = (unsigned short*)take((size_t)T_TOKENS * D_MOD * 2);
  unsigned short* xl  = (unsigned short*)take((size_t)T_TOKENS * D_MOD * 2);
  float* y          = (float*)take((size_t)P_CAP * D_MOD * 4);
  int*   top_i      = (int*)take((size_t)T_TOKENS * 2 * 4);
  float* gates      = (float*)take((size_t)T_TOKENS * 2 * 4);
  int*   counts     = (int*)take(64);
  int*   offsets    = (int*)take(64);
  int*   cursor     = (int*)take(64);
  int*   pair_token = (int*)take((size_t)P_CAP * 4);
  int*   pair_pos   = (int*)take((size_t)T_TOKENS * 2 * 4);

  // h chunk: rows_cap pairs of hi+lo bf16 rows (8KB per row)
  size_t h_avail = (ws_size > off) ? ws_size - off : 0;
  int rows_cap = (int)(h_avail / ((size_t)D_FF * 4));
  rows_cap &= ~(TPAD - 1);
  if (rows_cap > P_CAP) rows_cap = P_CAP;
  if (rows_cap < TPAD) rows_cap = TPAD;
  unsigned short* h_hi = (unsigned short*)(ws + off);
  unsigned short* h_lo = h_hi + (size_t)rows_cap * D_FF;

  k_prep<<<dim3(T_TOKENS * D_MOD / 2048), dim3(256), 0, stream>>>(x, xh, xl, counts);
  k_gate<<<dim3(T_TOKENS / 4), dim3(256), 0, stream>>>(x, Wg, bg, top_i, gates, counts);
  k_scan<<<dim3(1), dim3(256), 0, stream>>>(counts, offsets, cursor, pair_token);
  k_scatter<<<dim3(T_TOKENS / 256), dim3(256), 0, stream>>>(top_i, cursor, pair_token, pair_pos);
  k_transpose<<<dim3(D_FF / 32, D_MOD / 32, N_EXP), dim3(256), 0, stream>>>(W1, W1h, W1l, D_MOD, D_FF);
  k_transpose<<<dim3(D_MOD / 32, D_FF / 32, N_EXP), dim3(256), 0, stream>>>(W2, W2h, W2l, D_FF, D_MOD);

  for (int rb = 0; rb < P_CAP; rb += rows_cap) {
    int left = P_CAP - rb;
    int rows = (rows_cap < left) ? rows_cap : left;
    k_ffn1<<<dim3((rows / TPAD) * 16), dim3(256), 0, stream>>>(
        xh, xl, W1h, W1l, b1, pair_token, offsets, h_hi, h_lo, rb);
    k_ffn2<<<dim3((rows / 64) * 4), dim3(256), 0, stream>>>(
        h_hi, h_lo, W2h, W2l, offsets, y, rb);
  }
  k_combine<<<dim3(T_TOKENS * D_MOD / 1024), dim3(256), 0, stream>>>(
      y, pair_pos, top_i, gates, b2, out);
}

// Round 6
// 313.434 us; speedup vs baseline: 1.4879x; 1.3735x over previous
//
#include <hip/hip_runtime.h>

// MoE top-2 FFN, split-bf16 MFMA. Round 6:
//  - ZERO routing atomics: k_gate writes top_i/gates only; single-block k_route
//    builds counts/offsets/pair_token/pair_pos via LDS histogram + prefix scan
//    (round 5's k_gate/k_scatter did 16384 device atomics onto 16 words ~ 150us)
//  - GEMMs / transposes / prep / combine unchanged from round 5

#define T_TOKENS 4096
#define D_MOD 512
#define N_EXP 8
#define D_FF 2048
#define TPAD 128
#define P_CAP 9216       // 72*128 >= 8192 + 8*127

typedef __attribute__((ext_vector_type(4))) float f32x4_t;
typedef __attribute__((ext_vector_type(8))) short sh8;
typedef __attribute__((ext_vector_type(4))) unsigned short us4;

__device__ __forceinline__ unsigned short f2bh(float f) {
  unsigned u = __float_as_uint(f);
  return (unsigned short)((u + 0x7FFFu + ((u >> 16) & 1u)) >> 16);  // RNE
}
__device__ __forceinline__ float bh2f(unsigned short h) {
  return __uint_as_float(((unsigned)h) << 16);
}
__device__ __forceinline__ void gl_lds16(const void* g, void* l) {
  __builtin_amdgcn_global_load_lds(
      (const __attribute__((address_space(1))) unsigned int*)g,
      (__attribute__((address_space(3))) unsigned int*)l, 16, 0, 0);
}
__device__ __forceinline__ int xcd_swz(int orig, int nwg) {
  int q = nwg >> 3, r = nwg & 7, x = orig & 7, w = orig >> 3;
  return (x < r ? x * (q + 1) : r * (q + 1) + (x - r) * q) + w;
}

// ---------------- prep: x -> bf16 hi/lo ----------------

__global__ __launch_bounds__(256) void k_prep(const float* __restrict__ x,
    unsigned short* __restrict__ xh, unsigned short* __restrict__ xl) {
  int i = (blockIdx.x * 256 + threadIdx.x) * 8;
  float4 a = *(const float4*)(x + i);
  float4 b = *(const float4*)(x + i + 4);
  us4 h0 = {f2bh(a.x), f2bh(a.y), f2bh(a.z), f2bh(a.w)};
  us4 h1 = {f2bh(b.x), f2bh(b.y), f2bh(b.z), f2bh(b.w)};
  us4 l0 = {f2bh(a.x - bh2f(h0.x)), f2bh(a.y - bh2f(h0.y)),
            f2bh(a.z - bh2f(h0.z)), f2bh(a.w - bh2f(h0.w))};
  us4 l1 = {f2bh(b.x - bh2f(h1.x)), f2bh(b.y - bh2f(h1.y)),
            f2bh(b.z - bh2f(h1.z)), f2bh(b.w - bh2f(h1.w))};
  *(us4*)(xh + i) = h0; *(us4*)(xh + i + 4) = h1;
  *(us4*)(xl + i) = l0; *(us4*)(xl + i + 4) = l1;
}

// ---------------- gate (no atomics) ----------------

__global__ __launch_bounds__(256) void k_gate(const float* __restrict__ x,
    const float* __restrict__ Wg, const float* __restrict__ bg,
    int* __restrict__ top_i, float* __restrict__ gates) {
  __shared__ float wg_s[D_MOD * N_EXP];
  int tid = threadIdx.x;
  for (int i = tid; i < D_MOD * N_EXP; i += 256)
    wg_s[(i & 7) * D_MOD + (i >> 3)] = Wg[i];
  __syncthreads();
  int lane = tid & 63, w = tid >> 6;
  int t = blockIdx.x * 4 + w;
  const float* xr = x + (size_t)t * D_MOD;
  float acc[8];
#pragma unroll
  for (int e = 0; e < 8; ++e) acc[e] = 0.f;
#pragma unroll
  for (int it = 0; it < 2; ++it) {
    int d = it * 256 + lane * 4;
    float4 xv = *(const float4*)(xr + d);
#pragma unroll
    for (int e = 0; e < 8; ++e) {
      float4 wv = *(const float4*)(wg_s + e * D_MOD + d);
      acc[e] += xv.x * wv.x + xv.y * wv.y + xv.z * wv.z + xv.w * wv.w;
    }
  }
#pragma unroll
  for (int m = 32; m >= 1; m >>= 1)
#pragma unroll
    for (int e = 0; e < 8; ++e) acc[e] += __shfl_xor(acc[e], m);
  if (lane == 0) {
#pragma unroll
    for (int e = 0; e < 8; ++e) acc[e] += bg[e];
    int e0 = 0; float m0 = acc[0];
#pragma unroll
    for (int e = 1; e < 8; ++e) if (acc[e] > m0) { m0 = acc[e]; e0 = e; }
    int e1 = -1; float m1 = -3.4e38f;
#pragma unroll
    for (int e = 0; e < 8; ++e) if (e != e0 && acc[e] > m1) { m1 = acc[e]; e1 = e; }
    float g0 = 1.f / (1.f + __expf(m1 - m0));
    float g1 = 1.f - g0;
    top_i[t * 2] = e0; top_i[t * 2 + 1] = e1;
    gates[t * 2] = g0; gates[t * 2 + 1] = g1;
  }
}

// ---------------- route: single block, deterministic, no global atomics ----------------
// 256 threads x 16 tokens: LDS histogram -> per-expert exclusive scan -> padded
// offsets -> second pass assigns pair_token / pair_pos in token order.

__global__ __launch_bounds__(256) void k_route(const int* __restrict__ top_i,
    int* __restrict__ offsets, int* __restrict__ pair_token,
    int* __restrict__ pair_pos) {
  __shared__ int hist[256][9];   // padded stride 9 vs bank conflicts
  __shared__ int tot[8];
  __shared__ int offs[9];
  int tid = threadIdx.x;

  int te[32];
  int cnt[8];
#pragma unroll
  for (int e = 0; e < 8; ++e) cnt[e] = 0;
  int t0 = tid * 16;
#pragma unroll
  for (int j = 0; j < 16; ++j) {
    int2 v = *(const int2*)(top_i + (t0 + j) * 2);
    te[j * 2] = v.x; te[j * 2 + 1] = v.y;
    cnt[v.x]++; cnt[v.y]++;
  }
#pragma unroll
  for (int e = 0; e < 8; ++e) hist[tid][e] = cnt[e];
  __syncthreads();
  if (tid < 8) {                 // serial exclusive scan per expert (256 steps)
    int run = 0;
    for (int i = 0; i < 256; ++i) { int v = hist[i][tid]; hist[i][tid] = run; run += v; }
    tot[tid] = run;
  }
  __syncthreads();
  if (tid == 0) {
    int o = 0;
    for (int e = 0; e < N_EXP; ++e) {
      offs[e] = o; offsets[e] = o;
      o += (tot[e] + TPAD - 1) & ~(TPAD - 1);
    }
    offs[8] = o; offsets[8] = o;
  }
  __syncthreads();
  for (int i = tid; i < P_CAP; i += 256) pair_token[i] = -1;
  __syncthreads();
  int pos[8];
#pragma unroll
  for (int e = 0; e < 8; ++e) pos[e] = offs[e] + hist[tid][e];
#pragma unroll
  for (int j = 0; j < 32; ++j) {
    int e = te[j];
    int p = pos[e]++;
    pair_token[p] = t0 + (j >> 1);
    pair_pos[t0 * 2 + j] = p;
  }
}

// -------- weight transpose + hi/lo split: W[e][R][C] -> Wt[e][C][R] --------

__global__ __launch_bounds__(256) void k_transpose(const float* __restrict__ W,
    unsigned short* __restrict__ Wh, unsigned short* __restrict__ Wl, int R, int C) {
  __shared__ float tile[32][33];
  int e = blockIdx.z;
  int c0 = blockIdx.x * 32, r0 = blockIdx.y * 32;
  const float* src = W + (size_t)e * R * C;
  int tx = threadIdx.x & 31, ty = threadIdx.x >> 5;
#pragma unroll
  for (int i = 0; i < 4; ++i) {
    int r = ty + i * 8;
    tile[r][tx] = src[(size_t)(r0 + r) * C + c0 + tx];
  }
  __syncthreads();
  int cl = threadIdx.x >> 3;
  int r4 = (threadIdx.x & 7) * 4;
  float v0 = tile[r4 + 0][cl], v1 = tile[r4 + 1][cl];
  float v2 = tile[r4 + 2][cl], v3 = tile[r4 + 3][cl];
  us4 hv = {f2bh(v0), f2bh(v1), f2bh(v2), f2bh(v3)};
  us4 lv = {f2bh(v0 - bh2f(hv.x)), f2bh(v1 - bh2f(hv.y)),
            f2bh(v2 - bh2f(hv.z)), f2bh(v3 - bh2f(hv.w))};
  size_t o = ((size_t)e * C + c0 + cl) * R + r0 + r4;
  *(us4*)(Wh + o) = hv;
  *(us4*)(Wl + o) = lv;
}

// -------- GEMM1: h = relu(x @ W1 + b1), 128x128 tile, 4 waves, single-buf BK=32 --------
// LDS row: 128B = [hi 64B | lo 64B]; 16B slot s holds source chunk s^(row&7).

__global__ __launch_bounds__(256) void k_ffn1(
    const unsigned short* __restrict__ xh, const unsigned short* __restrict__ xl,
    const unsigned short* __restrict__ W1h, const unsigned short* __restrict__ W1l,
    const float* __restrict__ b1, const int* __restrict__ pair_token,
    const int* __restrict__ offsets, unsigned short* __restrict__ h_hi,
    unsigned short* __restrict__ h_lo, int rbase) {
  int wg = xcd_swz(blockIdx.x, gridDim.x);
  int rb = wg >> 4, fi = wg & 15;           // rb-major: x panel L2 reuse across fi
  int row0 = rbase + rb * 128;
  int total = offsets[N_EXP];
  if (row0 >= total) return;
  int f0 = fi * 128;
  int e = 0;
  while (offsets[e + 1] <= row0) ++e;

  __shared__ __align__(16) char lds[32768];   // A 16KB + B 16KB
  char* Ad = lds;
  char* Bd = lds + 16384;
  int tid = threadIdx.x;

  int s = tid & 7, rq = tid >> 3;             // rq 0..31
  int c = s ^ (rq & 7);
  const unsigned short* bA = (c < 4) ? xh : xl;
  const unsigned short* bB = (c < 4) ? W1h : W1l;
  size_t wb = (size_t)e * D_FF * D_MOD;
  const char* srcA[4]; const char* srcB[4];
#pragma unroll
  for (int i = 0; i < 4; ++i) {
    int t_ = pair_token[row0 + rq + i * 32];
    if (t_ < 0) t_ = 0;
    srcA[i] = (const char*)(bA + (size_t)t_ * D_MOD + (c & 3) * 8);
    srcB[i] = (const char*)(bB + wb + (size_t)(f0 + rq + i * 32) * D_MOD + (c & 3) * 8);
  }

  int lane = tid & 63, wid = tid >> 6;
  int wr = wid & 1, wc = wid >> 1;            // 2x2 waves, wave tile 64x64
  int lrow = lane & 15, kblk = lane >> 4;
  const f32x4_t zero = {0.f, 0.f, 0.f, 0.f};
  f32x4_t acc[4][4];
#pragma unroll
  for (int a = 0; a < 4; ++a)
#pragma unroll
    for (int b = 0; b < 4; ++b) acc[a][b] = zero;

  for (int ks = 0; ks < 16; ++ks) {
    int kb = ks * 64;                         // 32 elems * 2B
    __syncthreads();
#pragma unroll
    for (int i = 0; i < 4; ++i) gl_lds16(srcA[i] + kb, Ad + tid * 16 + i * 4096);
#pragma unroll
    for (int i = 0; i < 4; ++i) gl_lds16(srcB[i] + kb, Bd + tid * 16 + i * 4096);
    __syncthreads();
    sh8 ah[4], al[4], bh[4], bl[4];
#pragma unroll
    for (int rt = 0; rt < 4; ++rt) {
      int row = wr * 64 + rt * 16 + lrow;
      int base = row * 128;
      ah[rt] = *(const sh8*)(Ad + base + ((kblk ^ (row & 7)) << 4));
      al[rt] = *(const sh8*)(Ad + base + (((kblk + 4) ^ (row & 7)) << 4));
    }
#pragma unroll
    for (int ct = 0; ct < 4; ++ct) {
      int row = wc * 64 + ct * 16 + lrow;
      int base = row * 128;
      bh[ct] = *(const sh8*)(Bd + base + ((kblk ^ (row & 7)) << 4));
      bl[ct] = *(const sh8*)(Bd + base + (((kblk + 4) ^ (row & 7)) << 4));
    }
#pragma unroll
    for (int rt = 0; rt < 4; ++rt)
#pragma unroll
      for (int ct = 0; ct < 4; ++ct) {
        acc[rt][ct] = __builtin_amdgcn_mfma_f32_16x16x32_bf16(ah[rt], bh[ct], acc[rt][ct], 0, 0, 0);
        acc[rt][ct] = __builtin_amdgcn_mfma_f32_16x16x32_bf16(ah[rt], bl[ct], acc[rt][ct], 0, 0, 0);
        acc[rt][ct] = __builtin_amdgcn_mfma_f32_16x16x32_bf16(al[rt], bh[ct], acc[rt][ct], 0, 0, 0);
      }
  }

  // epilogue: relu(+b1), hi/lo split, vectorized store via 32KB LDS (two col halves)
  float b1v[4];
#pragma unroll
  for (int ct = 0; ct < 4; ++ct)
    b1v[ct] = b1[e * D_FF + f0 + wc * 64 + ct * 16 + lrow];
  int crow = row0 - rbase;
  float* hs = (float*)lds;                    // 128 x 64 f32 = 32KB
#pragma unroll
  for (int hf = 0; hf < 2; ++hf) {
    __syncthreads();
    if (wc == hf) {
#pragma unroll
      for (int rt = 0; rt < 4; ++rt)
#pragma unroll
        for (int ct = 0; ct < 4; ++ct)
#pragma unroll
          for (int j = 0; j < 4; ++j) {
            int row = wr * 64 + rt * 16 + kblk * 4 + j;   // C/D: row=(l>>4)*4+reg
            int col = ct * 16 + lrow;                     // col = l&15
            float v = fmaxf(acc[rt][ct][j] + b1v[ct], 0.f);
            int c4 = col >> 2;
            hs[row * 64 + ((c4 ^ ((row & 3) << 2)) << 2) + (col & 3)] = v;
          }
    }
    __syncthreads();
#pragma unroll
    for (int i = 0; i < 8; ++i) {
      int idx = tid + i * 256;                // 2048 float4 = 128 rows x 16
      int r = idx >> 4, c4 = idx & 15;
      float4 v = *(const float4*)(hs + r * 64 + ((c4 ^ ((r & 3) << 2)) << 2));
      us4 hv = {f2bh(v.x), f2bh(v.y), f2bh(v.z), f2bh(v.w)};
      us4 lv = {f2bh(v.x - bh2f(hv.x)), f2bh(v.y - bh2f(hv.y)),
                f2bh(v.z - bh2f(hv.z)), f2bh(v.w - bh2f(hv.w))};
      size_t o = (size_t)(crow + r) * D_FF + f0 + hf * 64 + c4 * 4;
      *(us4*)(h_hi + o) = hv;
      *(us4*)(h_lo + o) = lv;
    }
  }
}

// -------- GEMM2: y[pair] = h @ W2, 64x128 tile, full K=2048, NO atomics --------

__global__ __launch_bounds__(256) void k_ffn2(
    const unsigned short* __restrict__ h_hi, const unsigned short* __restrict__ h_lo,
    const unsigned short* __restrict__ W2h, const unsigned short* __restrict__ W2l,
    const int* __restrict__ offsets, float* __restrict__ y, int rbase) {
  int wg = xcd_swz(blockIdx.x, gridDim.x);
  int rb = wg >> 2, nblk = wg & 3;            // nblk fastest: h A-panel L2 reuse
  int row0 = rbase + rb * 64;
  int total = offsets[N_EXP];
  if (row0 >= total) return;
  int n0 = nblk * 128;
  int e = 0;
  while (offsets[e + 1] <= row0) ++e;

  __shared__ __align__(16) char lds[24576];   // A 8KB + B 16KB
  char* Ad = lds;
  char* Bd = lds + 8192;
  int tid = threadIdx.x;
  int crow = rb * 64;                         // h-buffer row (chunk-local)

  int s = tid & 7, rq = tid >> 3;
  int c = s ^ (rq & 7);
  const unsigned short* bA = (c < 4) ? h_hi : h_lo;
  const unsigned short* bB = (c < 4) ? W2h : W2l;
  size_t wb = (size_t)e * D_MOD * D_FF;
  const char* srcA[2]; const char* srcB[4];
#pragma unroll
  for (int i = 0; i < 2; ++i)
    srcA[i] = (const char*)(bA + (size_t)(crow + rq + i * 32) * D_FF + (c & 3) * 8);
#pragma unroll
  for (int i = 0; i < 4; ++i)
    srcB[i] = (const char*)(bB + wb + (size_t)(n0 + rq + i * 32) * D_FF + (c & 3) * 8);

  int lane = tid & 63, wc = tid >> 6;         // 1x4 waves, wave tile 64x32
  int lrow = lane & 15, kblk = lane >> 4;
  const f32x4_t zero = {0.f, 0.f, 0.f, 0.f};
  f32x4_t acc[4][2];
#pragma unroll
  for (int a = 0; a < 4; ++a)
#pragma unroll
    for (int b = 0; b < 2; ++b) acc[a][b] = zero;

  for (int ks = 0; ks < 64; ++ks) {
    int kb = ks * 64;
    __syncthreads();
#pragma unroll
    for (int i = 0; i < 2; ++i) gl_lds16(srcA[i] + kb, Ad + tid * 16 + i * 4096);
#pragma unroll
    for (int i = 0; i < 4; ++i) gl_lds16(srcB[i] + kb, Bd + tid * 16 + i * 4096);
    __syncthreads();
    sh8 ah[4], al[4], bh[2], bl[2];
#pragma unroll
    for (int rt = 0; rt < 4; ++rt) {
      int row = rt * 16 + lrow;
      int base = row * 128;
      ah[rt] = *(const sh8*)(Ad + base + ((kblk ^ (row & 7)) << 4));
      al[rt] = *(const sh8*)(Ad + base + (((kblk + 4) ^ (row & 7)) << 4));
    }
#pragma unroll
    for (int ct = 0; ct < 2; ++ct) {
      int row = wc * 32 + ct * 16 + lrow;
      int base = row * 128;
      bh[ct] = *(const sh8*)(Bd + base + ((kblk ^ (row & 7)) << 4));
      bl[ct] = *(const sh8*)(Bd + base + (((kblk + 4) ^ (row & 7)) << 4));
    }
#pragma unroll
    for (int rt = 0; rt < 4; ++rt)
#pragma unroll
      for (int ct = 0; ct < 2; ++ct) {
        acc[rt][ct] = __builtin_amdgcn_mfma_f32_16x16x32_bf16(ah[rt], bh[ct], acc[rt][ct], 0, 0, 0);
        acc[rt][ct] = __builtin_amdgcn_mfma_f32_16x16x32_bf16(ah[rt], bl[ct], acc[rt][ct], 0, 0, 0);
        acc[rt][ct] = __builtin_amdgcn_mfma_f32_16x16x32_bf16(al[rt], bh[ct], acc[rt][ct], 0, 0, 0);
      }
  }

  // epilogue: plain stores to per-pair y rows (each element written once)
#pragma unroll
  for (int rt = 0; rt < 4; ++rt)
#pragma unroll
    for (int j = 0; j < 4; ++j) {
      int row = rt * 16 + kblk * 4 + j;
#pragma unroll
      for (int ct = 0; ct < 2; ++ct) {
        int n = n0 + wc * 32 + ct * 16 + lrow;
        y[(size_t)(row0 + row) * D_MOD + n] = acc[rt][ct][j];
      }
    }
}

// -------- combine: out[t] = g0*(y[p0]+b2[e0]) + g1*(y[p1]+b2[e1]) --------

__global__ __launch_bounds__(256) void k_combine(const float* __restrict__ y,
    const int* __restrict__ pair_pos, const int* __restrict__ top_i,
    const float* __restrict__ gates, const float* __restrict__ b2,
    float* __restrict__ out) {
  int idx = blockIdx.x * 256 + threadIdx.x;   // 524288 float4 units
  int t = idx >> 7, q = (idx & 127) * 4;
  int p0 = pair_pos[t * 2], p1 = pair_pos[t * 2 + 1];
  float g0 = gates[t * 2], g1 = gates[t * 2 + 1];
  int e0 = top_i[t * 2], e1 = top_i[t * 2 + 1];
  float4 a = *(const float4*)(y + (size_t)p0 * D_MOD + q);
  float4 b = *(const float4*)(y + (size_t)p1 * D_MOD + q);
  float4 c0 = *(const float4*)(b2 + e0 * D_MOD + q);
  float4 c1 = *(const float4*)(b2 + e1 * D_MOD + q);
  float4 r;
  r.x = g0 * (a.x + c0.x) + g1 * (b.x + c1.x);
  r.y = g0 * (a.y + c0.y) + g1 * (b.y + c1.y);
  r.z = g0 * (a.z + c0.z) + g1 * (b.z + c1.z);
  r.w = g0 * (a.w + c0.w) + g1 * (b.w + c1.w);
  *(float4*)(out + (size_t)t * D_MOD + q) = r;
}

// ---------------- launch ----------------

extern "C" void kernel_launch(void* const* d_in, const int* in_sizes, int n_in,
                              void* d_out, int out_size, void* d_ws, size_t ws_size,
                              hipStream_t stream) {
  const float* x  = (const float*)d_in[0];
  const float* Wg = (const float*)d_in[1];
  const float* bg = (const float*)d_in[2];
  const float* W1 = (const float*)d_in[3];
  const float* b1 = (const float*)d_in[4];
  const float* W2 = (const float*)d_in[5];
  const float* b2 = (const float*)d_in[6];
  float* out = (float*)d_out;

  char* ws = (char*)d_ws;
  size_t off = 0;
  auto take = [&](size_t bytes) -> char* {
    char* p = ws + off;
    off += (bytes + 255) & ~(size_t)255;
    return p;
  };
  const size_t WELEMS = (size_t)N_EXP * D_MOD * D_FF;
  unsigned short* W1h = (unsigned short*)take(WELEMS * 2);
  unsigned short* W1l = (unsigned short*)take(WELEMS * 2);
  unsigned short* W2h = (unsigned short*)take(WELEMS * 2);
  unsigned short* W2l = (unsigned short*)take(WELEMS * 2);
  unsigned short* xh  = (unsigned short*)take((size_t)T_TOKENS * D_MOD * 2);
  unsigned short* xl  = (unsigned short*)take((size_t)T_TOKENS * D_MOD * 2);
  float* y          = (float*)take((size_t)P_CAP * D_MOD * 4);
  int*   top_i      = (int*)take((size_t)T_TOKENS * 2 * 4);
  float* gates      = (float*)take((size_t)T_TOKENS * 2 * 4);
  int*   offsets    = (int*)take(64);
  int*   pair_token = (int*)take((size_t)P_CAP * 4);
  int*   pair_pos   = (int*)take((size_t)T_TOKENS * 2 * 4);

  // h chunk: rows_cap pairs of hi+lo bf16 rows (8KB per row)
  size_t h_avail = (ws_size > off) ? ws_size - off : 0;
  int rows_cap = (int)(h_avail / ((size_t)D_FF * 4));
  rows_cap &= ~(TPAD - 1);
  if (rows_cap > P_CAP) rows_cap = P_CAP;
  if (rows_cap < TPAD) rows_cap = TPAD;
  unsigned short* h_hi = (unsigned short*)(ws + off);
  unsigned short* h_lo = h_hi + (size_t)rows_cap * D_FF;

  k_prep<<<dim3(T_TOKENS * D_MOD / 2048), dim3(256), 0, stream>>>(x, xh, xl);
  k_gate<<<dim3(T_TOKENS / 4), dim3(256), 0, stream>>>(x, Wg, bg, top_i, gates);
  k_route<<<dim3(1), dim3(256), 0, stream>>>(top_i, offsets, pair_token, pair_pos);
  k_transpose<<<dim3(D_FF / 32, D_MOD / 32, N_EXP), dim3(256), 0, stream>>>(W1, W1h, W1l, D_MOD, D_FF);
  k_transpose<<<dim3(D_MOD / 32, D_FF / 32, N_EXP), dim3(256), 0, stream>>>(W2, W2h, W2l, D_FF, D_MOD);

  for (int rb = 0; rb < P_CAP; rb += rows_cap) {
    int left = P_CAP - rb;
    int rows = (rows_cap < left) ? rows_cap : left;
    k_ffn1<<<dim3((rows / TPAD) * 16), dim3(256), 0, stream>>>(
        xh, xl, W1h, W1l, b1, pair_token, offsets, h_hi, h_lo, rb);
    k_ffn2<<<dim3((rows / 64) * 4), dim3(256), 0, stream>>>(
        h_hi, h_lo, W2h, W2l, offsets, y, rb);
  }
  k_combine<<<dim3(T_TOKENS * D_MOD / 1024), dim3(256), 0, stream>>>(
      y, pair_pos, top_i, gates, b2, out);
}